// Round 1
// baseline (453.457 us; speedup 1.0000x reference)
//
#include <hip/hip_runtime.h>

#define CROP  14
#define POS   196      // 14*14
#define HH    200
#define WW    304
#define CC    256
#define CGRP  16       // channels per block

__global__ __launch_bounds__(256) void crop_resize_kernel(
    const float* __restrict__ image,   // (8, 256, 200, 304)
    const float* __restrict__ boxes,   // (1000, 4) y1,x1,y2,x2
    const int*   __restrict__ bidx,    // (1000,)
    float*       __restrict__ out)     // (1000, 256, 14, 14)
{
    const int t = threadIdx.x;
    if (t >= POS) return;              // 196 active lanes of 256
    const int n  = blockIdx.x;         // box
    const int c0 = blockIdx.y * CGRP;  // channel group base
    const int yy = t / CROP;
    const int xx = t - yy * CROP;

    const float y1 = boxes[n * 4 + 0];
    const float x1 = boxes[n * 4 + 1];
    const float y2 = boxes[n * 4 + 2];
    const float x2 = boxes[n * 4 + 3];
    const int   b  = bidx[n];

    const float Hm1 = (float)(HH - 1);
    const float Wm1 = (float)(WW - 1);

    // in_y = y1*(H-1) + yy * (y2-y1)*(H-1)/(CROP-1)   (matches reference f32 math)
    const float stepy = (y2 - y1) * Hm1 * (1.0f / (float)(CROP - 1));
    const float stepx = (x2 - x1) * Wm1 * (1.0f / (float)(CROP - 1));
    const float in_y  = y1 * Hm1 + (float)yy * stepy;
    const float in_x  = x1 * Wm1 + (float)xx * stepx;

    const bool valid = (in_y >= 0.0f) && (in_y <= Hm1) &&
                       (in_x >= 0.0f) && (in_x <= Wm1);

    const float top_f  = floorf(in_y);
    const float left_f = floorf(in_x);
    const float yl = in_y - top_f;
    const float xl = in_x - left_f;

    const int top   = (int)fminf(fmaxf(top_f,        0.0f), Hm1);
    const int bot   = (int)fminf(fmaxf(ceilf(in_y),  0.0f), Hm1);
    const int left  = (int)fminf(fmaxf(left_f,       0.0f), Wm1);
    const int right = (int)fminf(fmaxf(ceilf(in_x),  0.0f), Wm1);

    const size_t plane = (size_t)HH * WW;
    const float* bimg  = image + ((size_t)b * CC + (size_t)c0) * plane;

    const int o_tl = top * WW + left;
    const int o_tr = top * WW + right;
    const int o_bl = bot * WW + left;
    const int o_br = bot * WW + right;

    float* po = out + ((size_t)n * CC + (size_t)c0) * POS + t;

    #pragma unroll 4
    for (int i = 0; i < CGRP; ++i) {
        const float* p = bimg + (size_t)i * plane;
        const float tl = p[o_tl];
        const float tr = p[o_tr];
        const float bl = p[o_bl];
        const float br = p[o_br];
        const float tv = tl + (tr - tl) * xl;
        const float bv = bl + (br - bl) * xl;
        float v = tv + (bv - tv) * yl;
        po[(size_t)i * POS] = valid ? v : 0.0f;
    }
}

extern "C" void kernel_launch(void* const* d_in, const int* in_sizes, int n_in,
                              void* d_out, int out_size, void* d_ws, size_t ws_size,
                              hipStream_t stream) {
    const float* image = (const float*)d_in[0];
    const float* boxes = (const float*)d_in[1];
    const int*   bidx  = (const int*)d_in[2];
    float*       out   = (float*)d_out;

    const int n_boxes = in_sizes[1] / 4;           // 1000
    dim3 grid(n_boxes, CC / CGRP);                 // (1000, 16) — box fast, channel-group slow
    dim3 block(256);
    crop_resize_kernel<<<grid, block, 0, stream>>>(image, boxes, bidx, out);
}

// Round 2
// 393.666 us; speedup vs baseline: 1.1519x; 1.1519x over previous
//
#include <hip/hip_runtime.h>

#define CROP   14
#define POS    196     // 14*14
#define HH     200
#define WW     304
#define CC     256
#define NIMG   8
#define QROWS  50      // top-rows per quarter
#define MAXBOX 1024

// Block = (image b, quarter q, channel c). Loads tile rows [q*50, q*50+rows)
// of plane (b,c) into LDS, then computes every output sample whose clipped
// top row lies in this quarter, for every box of image b.
__global__ __launch_bounds__(512) void crop_tile_kernel(
    const float* __restrict__ image,   // (8,256,200,304)
    const float* __restrict__ boxes,   // (1000,4) y1,x1,y2,x2
    const int*   __restrict__ bidx,    // (1000,)
    float*       __restrict__ out,     // (1000,256,14,14)
    int n_boxes)
{
    __shared__ float tile[51 * WW];    // 62016 B
    __shared__ int   list[MAXBOX];
    __shared__ int   cnt;

    const int bq = blockIdx.x;         // 0..31  (image*4 + quarter)
    const int b  = bq >> 2;
    const int q  = bq & 3;
    const int c  = blockIdx.y;
    const int t  = threadIdx.x;

    const int base  = q * QROWS;                    // first tile row
    const int rows  = (q == 3) ? 50 : 51;           // tile rows loaded
    const int topHi = (q == 3) ? 199 : base + QROWS - 1; // last top owned

    if (t == 0) cnt = 0;
    __syncthreads();

    // ---- build list of boxes of image b overlapping this quarter ----
    for (int n = t; n < n_boxes; n += 512) {
        if (bidx[n] == b) {
            const float y1 = boxes[4 * n + 0];
            const float y2 = boxes[4 * n + 2];
            const float a  = y1 * 199.0f;
            const float bb = y2 * 199.0f;
            const float lo = fminf(a, bb);
            const float hi = fmaxf(a, bb);
            const int tlo = (int)fminf(fmaxf(floorf(lo), 0.0f), 199.0f);
            const int thi = (int)fminf(fmaxf(floorf(hi), 0.0f), 199.0f);
            if (thi >= base && tlo <= topHi) {
                const int p = atomicAdd(&cnt, 1);
                list[p] = n;
            }
        }
    }

    // ---- coalesced tile load (float4) ----
    {
        const float* src = image + ((size_t)b * CC + (size_t)c) * (size_t)(HH * WW)
                                 + (size_t)base * WW;
        const int nvec = (rows * WW) >> 2;          // 3876 or 3800, exact
        const float4* s4 = (const float4*)src;
        float4* t4 = (float4*)tile;
        for (int i = t; i < nvec; i += 512) t4[i] = s4[i];
    }
    __syncthreads();

    // ---- compute: 2 boxes at a time (threads 0..391), 196 samples each ----
    const int g = t / POS;             // box slot 0/1 (g==2 idles)
    const int s = t - g * POS;
    const int yy = s / CROP;
    const int xx = s - yy * CROP;
    const int total = cnt;
    const int nIter = (total + 1) >> 1;

    if (g < 2) {
        for (int it = 0; it < nIter; ++it) {
            const int idx = it * 2 + g;
            if (idx < total) {
                const int nn = list[idx];
                const float y1 = boxes[4 * nn + 0];
                const float x1 = boxes[4 * nn + 1];
                const float y2 = boxes[4 * nn + 2];
                const float x2 = boxes[4 * nn + 3];

                const float in_y = y1 * 199.0f + (float)yy * ((y2 - y1) * 199.0f * (1.0f / 13.0f));
                const float in_x = x1 * 303.0f + (float)xx * ((x2 - x1) * 303.0f * (1.0f / 13.0f));

                const float tf = floorf(in_y);
                const int topc = (int)fminf(fmaxf(tf, 0.0f), 199.0f);
                if (topc >= base && topc <= topHi) {
                    const float lf = floorf(in_x);
                    const int botc   = (int)fminf(fmaxf(ceilf(in_y), 0.0f), 199.0f);
                    const int leftc  = (int)fminf(fmaxf(lf, 0.0f), 303.0f);
                    const int rightc = (int)fminf(fmaxf(ceilf(in_x), 0.0f), 303.0f);
                    const float yl = in_y - tf;
                    const float xl = in_x - lf;

                    const int r0 = topc - base;
                    const int r1 = botc - base;
                    const float tl = tile[r0 * WW + leftc];
                    const float tr = tile[r0 * WW + rightc];
                    const float bl = tile[r1 * WW + leftc];
                    const float br = tile[r1 * WW + rightc];
                    const float tv = tl + (tr - tl) * xl;
                    const float bv = bl + (br - bl) * xl;
                    const float v  = tv + (bv - tv) * yl;

                    const bool valid = (in_y >= 0.0f) && (in_y <= 199.0f) &&
                                       (in_x >= 0.0f) && (in_x <= 303.0f);
                    out[((size_t)nn * CC + (size_t)c) * POS + s] = valid ? v : 0.0f;
                }
            }
        }
    }
}

extern "C" void kernel_launch(void* const* d_in, const int* in_sizes, int n_in,
                              void* d_out, int out_size, void* d_ws, size_t ws_size,
                              hipStream_t stream) {
    const float* image = (const float*)d_in[0];
    const float* boxes = (const float*)d_in[1];
    const int*   bidx  = (const int*)d_in[2];
    float*       out   = (float*)d_out;

    const int n_boxes = in_sizes[1] / 4;   // 1000
    dim3 grid(NIMG * 4, CC);               // (32, 256)
    dim3 block(512);
    crop_tile_kernel<<<grid, block, 0, stream>>>(image, boxes, bidx, out, n_boxes);
}

// Round 3
// 291.331 us; speedup vs baseline: 1.5565x; 1.3513x over previous
//
#include <hip/hip_runtime.h>

#define CROP  14
#define POS   196
#define HH    200
#define WW    304
#define CC    256
#define NIMG  8
#define TR    25          // top-rows owned per tile
#define NT    8           // tiles per image (200/25)
#define NBIN  (NIMG*NT)   // 64
#define ECAP  512         // max run-entries per bin (worst case ~170)

// ws layout: [0,256): u32 counts[64]; [256, 256+64*512*4): u32 entries[64][512]
// entry encoding: n | (yyLo<<16) | (nRows<<24)

__global__ void build_entries(const float* __restrict__ boxes,
                              const int*   __restrict__ bidx,
                              int n_boxes,
                              unsigned* __restrict__ counts,
                              unsigned* __restrict__ entries)
{
    const int n = blockIdx.x * 256 + threadIdx.x;
    if (n >= n_boxes) return;
    const float y1 = boxes[4*n+0], y2 = boxes[4*n+2];
    const int b = bidx[n];
    int prevTile = -1, yyLo = 0;
    for (int yy = 0; yy < 14; ++yy) {
        // EXACTLY the same expression shape as crop_compute (bit-identical)
        const float in_y = y1*199.0f + (float)yy*((y2-y1)*199.0f*(1.0f/13.0f));
        const float tf = floorf(in_y);
        const int top = (int)fminf(fmaxf(tf, 0.0f), 199.0f);
        const int tile = top / TR;
        if (tile != prevTile) {
            if (prevTile >= 0) {
                const unsigned idx = atomicAdd(&counts[b*NT + prevTile], 1u);
                if (idx < ECAP)
                    entries[(b*NT + prevTile)*ECAP + idx] =
                        (unsigned)n | ((unsigned)yyLo << 16) | ((unsigned)(yy - yyLo) << 24);
            }
            prevTile = tile; yyLo = yy;
        }
    }
    const unsigned idx = atomicAdd(&counts[b*NT + prevTile], 1u);
    if (idx < ECAP)
        entries[(b*NT + prevTile)*ECAP + idx] =
            (unsigned)n | ((unsigned)yyLo << 16) | ((unsigned)(14 - yyLo) << 24);
}

__global__ __launch_bounds__(512) void crop_compute(
    const float*    __restrict__ image,    // (8,256,200,304)
    const float*    __restrict__ boxes,    // (1000,4)
    const unsigned* __restrict__ counts,
    const unsigned* __restrict__ entries,
    float*          __restrict__ out)      // (1000,256,14,14)
{
    __shared__ float    tile[26 * WW];     // 31,616 B
    __shared__ unsigned ent[ECAP];
    __shared__ int      incl[ECAP];
    __shared__ int      totS;

    const int bin = blockIdx.x;            // b*8 + tile
    const int b   = bin >> 3;
    const int tl  = bin & 7;
    const int c   = blockIdx.y;
    const int t   = threadIdx.x;
    const int base = tl * TR;
    const int rows = (tl == NT-1) ? TR : TR + 1;   // load one extra row for bot

    const int E = min((int)counts[bin], ECAP);
    if (t < E) {
        const unsigned e = entries[bin*ECAP + t];
        ent[t]  = e;
        incl[t] = (int)((e >> 24) & 0xFF) * CROP;  // samples in this run
    }
    __syncthreads();
    // inclusive Hillis-Steele scan over E (<=512)
    for (int off = 1; off < E; off <<= 1) {
        int v = (t >= off && t < E) ? incl[t-off] : 0;
        __syncthreads();
        if (t < E) incl[t] += v;
        __syncthreads();
    }
    if (t == 0) totS = (E > 0) ? incl[E-1] : 0;
    __syncthreads();
    const int S = totS;
    if (S == 0) return;

    // coalesced tile load
    {
        const float* src = image + ((size_t)b * CC + (size_t)c) * (size_t)(HH*WW)
                                 + (size_t)base * WW;
        const int nv = (rows * WW) >> 2;
        const float4* s4 = (const float4*)src;
        float4* t4 = (float4*)tile;
        for (int i = t; i < nv; i += 512) t4[i] = s4[i];
    }
    __syncthreads();

    for (int k = t; k < S; k += 512) {
        // smallest e with incl[e] > k
        int lo = 0, hi = E - 1;
        while (lo < hi) { const int mid = (lo + hi) >> 1; if (incl[mid] > k) hi = mid; else lo = mid + 1; }
        const unsigned en = ent[lo];
        const int n    = (int)(en & 0xFFFF);
        const int yyLo = (int)((en >> 16) & 0xFF);
        const int nR   = (int)((en >> 24) & 0xFF);
        const int local = k - (incl[lo] - nR * CROP);
        const int dy = local / CROP;
        const int yy = yyLo + dy;
        const int xx = local - dy * CROP;

        const float y1 = boxes[4*n+0], x1 = boxes[4*n+1];
        const float y2 = boxes[4*n+2], x2 = boxes[4*n+3];
        const float in_y = y1*199.0f + (float)yy*((y2-y1)*199.0f*(1.0f/13.0f));
        const float in_x = x1*303.0f + (float)xx*((x2-x1)*303.0f*(1.0f/13.0f));

        const float tf = floorf(in_y), lf = floorf(in_x);
        const int topc   = (int)fminf(fmaxf(tf,          0.0f), 199.0f);
        const int botc   = (int)fminf(fmaxf(ceilf(in_y), 0.0f), 199.0f);
        const int leftc  = (int)fminf(fmaxf(lf,          0.0f), 303.0f);
        const int rightc = (int)fminf(fmaxf(ceilf(in_x), 0.0f), 303.0f);
        const float yl = in_y - tf, xl = in_x - lf;

        const int r0 = topc - base, r1 = botc - base;
        const float tlv = tile[r0*WW + leftc];
        const float trv = tile[r0*WW + rightc];
        const float blv = tile[r1*WW + leftc];
        const float brv = tile[r1*WW + rightc];
        const float tv = tlv + (trv - tlv) * xl;
        const float bv = blv + (brv - blv) * xl;
        const float v  = tv + (bv - tv) * yl;

        const bool valid = (in_y >= 0.0f) && (in_y <= 199.0f) &&
                           (in_x >= 0.0f) && (in_x <= 303.0f);
        out[((size_t)n * CC + (size_t)c) * POS + yy*CROP + xx] = valid ? v : 0.0f;
    }
}

extern "C" void kernel_launch(void* const* d_in, const int* in_sizes, int n_in,
                              void* d_out, int out_size, void* d_ws, size_t ws_size,
                              hipStream_t stream) {
    const float* image = (const float*)d_in[0];
    const float* boxes = (const float*)d_in[1];
    const int*   bidx  = (const int*)d_in[2];
    float*       out   = (float*)d_out;
    const int n_boxes = in_sizes[1] / 4;   // 1000

    unsigned* counts  = (unsigned*)d_ws;
    unsigned* entries = counts + NBIN;

    hipMemsetAsync(counts, 0, NBIN * sizeof(unsigned), stream);
    build_entries<<<dim3((n_boxes + 255) / 256), dim3(256), 0, stream>>>(
        boxes, bidx, n_boxes, counts, entries);
    crop_compute<<<dim3(NBIN, CC), dim3(512), 0, stream>>>(
        image, boxes, counts, entries, out);
}

// Round 4
// 213.005 us; speedup vs baseline: 2.1289x; 1.3677x over previous
//
#include <hip/hip_runtime.h>

#define CROP  14
#define POS   196
#define HH    200
#define WW    304
#define CC    256
#define NIMG  8
#define TR    25          // top-rows owned per tile
#define NT    8           // tiles per image
#define NBIN  (NIMG*NT)   // 64

// ws layout (bytes):
// [0,256):    u32 counts[64]
// [256,512):  u32 offsets[64]
// [512,768):  u32 cursors[64]
// [1024, 1024+196000*16): int4 desc[]   (3.14 MB total)
// desc: .x = offtl | dx<<13 | dy<<14 | valid<<15 ; .y = n*CC*POS + s ; .z = xl ; .w = yl

__device__ __forceinline__ int top_row(float y1, float y2, int yy) {
    const float in_y = y1*199.0f + (float)yy*((y2-y1)*199.0f*(1.0f/13.0f));
    return (int)fminf(fmaxf(floorf(in_y), 0.0f), 199.0f);
}

__global__ void count_runs(const float* __restrict__ boxes, const int* __restrict__ bidx,
                           int n_boxes, unsigned* __restrict__ counts)
{
    const int n = blockIdx.x*256 + threadIdx.x;
    if (n >= n_boxes) return;
    const float y1 = boxes[4*n+0], y2 = boxes[4*n+2];
    const int b = bidx[n];
    int prev = -1, yyLo = 0;
    for (int yy = 0; yy < 14; ++yy) {
        const int tile = top_row(y1, y2, yy) / TR;
        if (tile != prev) {
            if (prev >= 0) atomicAdd(&counts[b*NT+prev], (unsigned)((yy-yyLo)*CROP));
            prev = tile; yyLo = yy;
        }
    }
    atomicAdd(&counts[b*NT+prev], (unsigned)((14-yyLo)*CROP));
}

__global__ void scan_bins(const unsigned* __restrict__ counts,
                          unsigned* __restrict__ offsets, unsigned* __restrict__ cursors)
{
    if (threadIdx.x == 0) {
        unsigned acc = 0;
        for (int i = 0; i < NBIN; ++i) { offsets[i] = acc; cursors[i] = acc; acc += counts[i]; }
    }
}

__global__ __launch_bounds__(256) void emit_desc(
    const float* __restrict__ boxes, const int* __restrict__ bidx,
    unsigned* __restrict__ cursors, int4* __restrict__ desc)
{
    __shared__ int rowSlot[14];
    const int n = blockIdx.x;
    const int t = threadIdx.x;
    const float y1 = boxes[4*n+0], x1 = boxes[4*n+1];
    const float y2 = boxes[4*n+2], x2 = boxes[4*n+3];
    const int b = bidx[n];

    if (t == 0) {
        int tiles[14];
        for (int yy = 0; yy < 14; ++yy) tiles[yy] = top_row(y1, y2, yy) / TR;
        for (int yy = 0; yy < 14; ++yy) {
            if (yy == 0 || tiles[yy] != tiles[yy-1]) {
                int hi = yy;
                while (hi+1 < 14 && tiles[hi+1] == tiles[yy]) ++hi;
                const unsigned base = atomicAdd(&cursors[b*NT + tiles[yy]],
                                                (unsigned)((hi-yy+1)*CROP));
                for (int r = yy; r <= hi; ++r) rowSlot[r] = (int)base + (r-yy)*CROP;
            }
        }
    }
    __syncthreads();

    if (t < POS) {
        const int yy = t / CROP, xx = t - yy*CROP;
        const float in_y = y1*199.0f + (float)yy*((y2-y1)*199.0f*(1.0f/13.0f));
        const float in_x = x1*303.0f + (float)xx*((x2-x1)*303.0f*(1.0f/13.0f));
        const float tf = floorf(in_y), lf = floorf(in_x);
        const int topc   = (int)fminf(fmaxf(tf,          0.0f), 199.0f);
        const int botc   = (int)fminf(fmaxf(ceilf(in_y), 0.0f), 199.0f);
        const int leftc  = (int)fminf(fmaxf(lf,          0.0f), 303.0f);
        const int rightc = (int)fminf(fmaxf(ceilf(in_x), 0.0f), 303.0f);
        const int tile = topc / TR;
        const int r0   = topc - tile*TR;
        const unsigned w0 = (unsigned)(r0*WW + leftc)
                          | ((unsigned)(rightc - leftc) << 13)
                          | ((unsigned)(botc - topc)    << 14)
                          | ((unsigned)((in_y >= 0.0f) & (in_y <= 199.0f) &
                                        (in_x >= 0.0f) & (in_x <= 303.0f)) << 15);
        int4 d;
        d.x = (int)w0;
        d.y = n*CC*POS + t;
        d.z = __float_as_int(in_x - lf);
        d.w = __float_as_int(in_y - tf);
        desc[rowSlot[yy] + xx] = d;
    }
}

__global__ __launch_bounds__(512) void crop_compute(
    const float*    __restrict__ image,
    const unsigned* __restrict__ counts,
    const unsigned* __restrict__ offsets,
    const int4*     __restrict__ desc,
    float*          __restrict__ out)
{
    __shared__ float tile[26 * WW];        // 31,616 B
    const int c   = blockIdx.x;
    const int bin = blockIdx.y;
    const int b   = bin >> 3;
    const int tl  = bin & 7;
    const int t   = threadIdx.x;
    const int base = tl * TR;
    const int rows = (tl == NT-1) ? TR : TR + 1;

    const int S    = (int)counts[bin];
    const int off0 = (int)offsets[bin];

    {
        const float* src = image + ((size_t)b*CC + (size_t)c)*(size_t)(HH*WW)
                                 + (size_t)base*WW;
        const int nv = (rows * WW) >> 2;
        const float4* s4 = (const float4*)src;
        float4* t4 = (float4*)tile;
        for (int i = t; i < nv; i += 512) t4[i] = s4[i];
    }
    __syncthreads();
    if (S == 0) return;

    const size_t cbase = (size_t)c * POS;
    for (int k = t; k < S; k += 512) {
        const int4 d = desc[off0 + k];
        const unsigned w0 = (unsigned)d.x;
        const int off = (int)(w0 & 0x1FFFu);
        const int dx  = (int)((w0 >> 13) & 1u);
        const int dyw = ((w0 >> 14) & 1u) ? WW : 0;
        const float xl = __int_as_float(d.z);
        const float yl = __int_as_float(d.w);
        const float tlv = tile[off];
        const float trv = tile[off + dx];
        const float blv = tile[off + dyw];
        const float brv = tile[off + dyw + dx];
        const float tv = tlv + (trv - tlv) * xl;
        const float bv = blv + (brv - blv) * xl;
        float v = tv + (bv - tv) * yl;
        v = (w0 & 0x8000u) ? v : 0.0f;
        out[(size_t)(unsigned)d.y + cbase] = v;
    }
}

extern "C" void kernel_launch(void* const* d_in, const int* in_sizes, int n_in,
                              void* d_out, int out_size, void* d_ws, size_t ws_size,
                              hipStream_t stream) {
    const float* image = (const float*)d_in[0];
    const float* boxes = (const float*)d_in[1];
    const int*   bidx  = (const int*)d_in[2];
    float*       out   = (float*)d_out;
    const int n_boxes = in_sizes[1] / 4;     // 1000

    unsigned* counts  = (unsigned*)d_ws;
    unsigned* offsets = counts + 64;
    unsigned* cursors = counts + 128;
    int4*     desc    = (int4*)((char*)d_ws + 1024);

    hipMemsetAsync(counts, 0, 256, stream);
    count_runs<<<dim3((n_boxes+255)/256), dim3(256), 0, stream>>>(boxes, bidx, n_boxes, counts);
    scan_bins<<<dim3(1), dim3(64), 0, stream>>>(counts, offsets, cursors);
    emit_desc<<<dim3(n_boxes), dim3(256), 0, stream>>>(boxes, bidx, cursors, desc);
    crop_compute<<<dim3(CC, NBIN), dim3(512), 0, stream>>>(image, counts, offsets, desc, out);
}